// Round 1
// baseline (73.930 us; speedup 1.0000x reference)
//
#include <hip/hip_runtime.h>
#include <math.h>

// Problem constants (derived at launch from in_sizes where it matters)
constexpr int GROUPS   = 16;              // pairs (undirected edges) per block
constexpr int XSTRIDE  = 36;              // padded per-d row stride in words (H=32 + 4 pad)
constexpr int XROW     = 4 * XSTRIDE;     // 144 words per node row (4 x 36)
constexpr int GBUF     = 2 * XROW + 8;    // 296 words per group; 296 % 32 == 8 -> 2-way bank aliasing only
constexpr int SIMSTRIDE = 40;             // 32 sims + 8 pad -> group base offset 8 mod 32

__device__ __forceinline__ float fast_tanh(float v) {
    // tanh(x) = 1 - 2/(exp(2x)+1)  (exact identity; exp/rcp are ~1ulp HW approx)
    float ex = __expf(2.0f * v);
    return 1.0f - 2.0f * __builtin_amdgcn_rcpf(ex + 1.0f);
}

__global__ __launch_bounds__(256) void sheaf_pair_kernel(
    const float* __restrict__ x,          // (N, 4, 32)
    const float* __restrict__ Maps,       // (E, 4, 4)
    const float* __restrict__ W1,         // (16, 16)
    const float* __restrict__ b1,         // (16,)
    const int*   __restrict__ edge_index, // (2, E)
    const int*   __restrict__ opp_idx,    // (E,)
    float*       __restrict__ out,        // (E, 4, 4)
    int E, int EHALF)
{
    __shared__ __align__(16) float xbuf[GROUPS * GBUF];       // 18944 B
    __shared__ __align__(16) float gram[GROUPS * 48];         // Gu[16] Gv[16] C[16] per group
    __shared__ __align__(16) float simsb[GROUPS * SIMSTRIDE]; // sims1[16] sims2[16] + pad

    const int tid = threadIdx.x;
    const int g   = tid >> 4;     // group (pair slot) in block
    const int l   = tid & 15;     // lane within group
    const int di  = l >> 2;       // row index i (and gram row d)
    const int kj  = l & 3;        // col index k

    const int pair  = blockIdx.x * GROUPS + g;
    const bool valid = pair < EHALF;

    // W1 row + bias for this lane's output element (L1 broadcast across groups)
    const float4* Wp = (const float4*)(W1 + l * 16);
    float4 w0 = Wp[0], w1 = Wp[1], w2 = Wp[2], w3 = Wp[3];
    float bias = b1[l];

    int s = 0, t = 0, e2 = 0;
    if (valid) {
        s  = edge_index[pair];        // source of e1
        t  = edge_index[E + pair];    // target of e1
        e2 = opp_idx[pair];           // opposite (reversed) edge index
    }

    float* xg = xbuf + g * GBUF;
    if (valid) {
        // cooperative load x[s], x[t] (128 floats each) into padded LDS
        // lane l covers flat words [8l, 8l+8): d = l>>2, h = 8*(l&3)
        const float4* xs = (const float4*)(x + (size_t)s * 128);
        const float4* xt = (const float4*)(x + (size_t)t * 128);
        const int d0 = l >> 2, h0 = (l & 3) * 8;
        float4 a0 = xs[l * 2];
        float4 a1 = xs[l * 2 + 1];
        float4 c0 = xt[l * 2];
        float4 c1 = xt[l * 2 + 1];
        *(float4*)(xg + d0 * XSTRIDE + h0)            = a0;
        *(float4*)(xg + d0 * XSTRIDE + h0 + 4)        = a1;
        *(float4*)(xg + XROW + d0 * XSTRIDE + h0)     = c0;
        *(float4*)(xg + XROW + d0 * XSTRIDE + h0 + 4) = c1;
    }

    // hoist Maps loads (latency hidden under gram loop)
    float4 m1 = {0,0,0,0}, m2 = {0,0,0,0};
    if (valid) {
        m1 = *(const float4*)(Maps + (size_t)pair * 16 + di * 4);
        m2 = *(const float4*)(Maps + (size_t)e2   * 16 + di * 4);
    }

    __syncthreads();

    // grams: lane (di,kj) computes Gu[d][k], Gv[d][k], C[d][k] = sum_h xv[d][h]*xu[k][h]
    float4 accU = {0,0,0,0}, accV = {0,0,0,0}, accC = {0,0,0,0};
    if (valid) {
        const float* xu = xg;
        const float* xv = xg + XROW;
        #pragma unroll
        for (int hc = 0; hc < 8; ++hc) {
            float4 ud = *(const float4*)(xu + di * XSTRIDE + hc * 4);
            float4 uk = *(const float4*)(xu + kj * XSTRIDE + hc * 4);
            float4 vd = *(const float4*)(xv + di * XSTRIDE + hc * 4);
            float4 vk = *(const float4*)(xv + kj * XSTRIDE + hc * 4);
            accU.x = fmaf(ud.x, uk.x, accU.x); accU.y = fmaf(ud.y, uk.y, accU.y);
            accU.z = fmaf(ud.z, uk.z, accU.z); accU.w = fmaf(ud.w, uk.w, accU.w);
            accV.x = fmaf(vd.x, vk.x, accV.x); accV.y = fmaf(vd.y, vk.y, accV.y);
            accV.z = fmaf(vd.z, vk.z, accV.z); accV.w = fmaf(vd.w, vk.w, accV.w);
            accC.x = fmaf(vd.x, uk.x, accC.x); accC.y = fmaf(vd.y, uk.y, accC.y);
            accC.z = fmaf(vd.z, uk.z, accC.z); accC.w = fmaf(vd.w, uk.w, accC.w);
        }
    }
    float Gu = accU.x + accU.y + accU.z + accU.w;
    float Gv = accV.x + accV.y + accV.z + accV.w;
    float Cc = accC.x + accC.y + accC.z + accC.w;

    float* gr = gram + g * 48;
    if (valid) {
        gr[l]      = Gu;   // Gu[d][k] row-major
        gr[16 + l] = Gv;
        gr[32 + l] = Cc;   // C[d][k]
    }
    __syncthreads();

    // sims for both orientations; lane = (i=di, k=kj)
    float s1 = 0.f, s2 = 0.f;
    if (valid) {
        // sims1 = 2*( M1[i,:] . Gu[:,k]  -  M2[i,:] . C[:,k] )
        float gss = m1.x * gr[0 + kj] + m1.y * gr[4 + kj] + m1.z * gr[8 + kj] + m1.w * gr[12 + kj];
        float gts = m2.x * gr[32 + kj] + m2.y * gr[36 + kj] + m2.z * gr[40 + kj] + m2.w * gr[44 + kj];
        s1 = 2.0f * (gss - gts);
        // sims2 = 2*( M2[i,:] . Gv[:,k]  -  M1[i,:] . C[k,:] )   (C^T)
        float gss2 = m2.x * gr[16 + kj] + m2.y * gr[20 + kj] + m2.z * gr[24 + kj] + m2.w * gr[28 + kj];
        float gts2 = m1.x * gr[32 + kj * 4 + 0] + m1.y * gr[32 + kj * 4 + 1]
                   + m1.z * gr[32 + kj * 4 + 2] + m1.w * gr[32 + kj * 4 + 3];
        s2 = 2.0f * (gss2 - gts2);
    }

    float* sb = simsb + g * SIMSTRIDE;
    if (valid) {
        sb[l]      = s1;
        sb[16 + l] = s2;
    }
    __syncthreads();

    if (valid) {
        // linear: out[p] = tanh( b[p] + sum_q W1[p][q] * sims[q] ), p = l
        float a1 = bias, a2 = bias;
        a1 += w0.x * sb[0]  + w0.y * sb[1]  + w0.z * sb[2]  + w0.w * sb[3];
        a1 += w1.x * sb[4]  + w1.y * sb[5]  + w1.z * sb[6]  + w1.w * sb[7];
        a1 += w2.x * sb[8]  + w2.y * sb[9]  + w2.z * sb[10] + w2.w * sb[11];
        a1 += w3.x * sb[12] + w3.y * sb[13] + w3.z * sb[14] + w3.w * sb[15];
        a2 += w0.x * sb[16] + w0.y * sb[17] + w0.z * sb[18] + w0.w * sb[19];
        a2 += w1.x * sb[20] + w1.y * sb[21] + w1.z * sb[22] + w1.w * sb[23];
        a2 += w2.x * sb[24] + w2.y * sb[25] + w2.z * sb[26] + w2.w * sb[27];
        a2 += w3.x * sb[28] + w3.y * sb[29] + w3.z * sb[30] + w3.w * sb[31];

        out[(size_t)pair * 16 + l] = fast_tanh(a1);
        out[(size_t)e2   * 16 + l] = fast_tanh(a2);
    }
}

extern "C" void kernel_launch(void* const* d_in, const int* in_sizes, int n_in,
                              void* d_out, int out_size, void* d_ws, size_t ws_size,
                              hipStream_t stream) {
    const float* x          = (const float*)d_in[0];
    const float* Maps       = (const float*)d_in[1];
    const float* W1         = (const float*)d_in[2];
    const float* b1         = (const float*)d_in[3];
    const int*   edge_index = (const int*)d_in[4];
    const int*   opp_idx    = (const int*)d_in[5];

    const int E     = in_sizes[5];   // number of directed edges
    const int EHALF = E / 2;         // undirected pairs (first half pairs with second)

    const int blocks = (EHALF + GROUPS - 1) / GROUPS;
    sheaf_pair_kernel<<<blocks, 256, 0, stream>>>(
        x, Maps, W1, b1, edge_index, opp_idx, (float*)d_out, E, EHALF);
}